// Round 7
// baseline (1082214.634 us; speedup 1.0000x reference)
//
#include <hip/hip_runtime.h>

#define TT 256
#define BB 32
#define HH 512
#define EE 512
#define GG 2048
#define MM 8192
#define NWG 32   // column-groups (WGs) per direction in lstm_rec

typedef __attribute__((ext_vector_type(8))) short bf16x8;
typedef __attribute__((ext_vector_type(4))) float f32x4;
typedef __attribute__((ext_vector_type(4))) unsigned short us4;
typedef unsigned long long ull;

__device__ inline float b2f(unsigned short u) {
    union { unsigned int i; float f; } v; v.i = ((unsigned int)u) << 16; return v.f;
}
__device__ inline unsigned short f2b(float f) {
    union { float f; unsigned int i; } v; v.f = f;
    unsigned int x = v.i;
    return (unsigned short)((x + 0x7FFFu + ((x >> 16) & 1u)) >> 16);
}
__device__ inline float sigm(float x) { return 1.f / (1.f + __expf(-x)); }
__device__ inline float tanh_f(float x) {
    float ax = fminf(fabsf(x), 12.f);
    float e = __expf(2.f * ax);
    float r = (e - 1.f) / (e + 1.f);
    return x < 0.f ? -r : r;
}

// ---------------- prep + embed fused ----------------
__global__ void prep_embed_k(const int* __restrict__ ids, const float* __restrict__ emb,
                             const float* __restrict__ wihf, const float* __restrict__ whhf,
                             const float* __restrict__ wihb, const float* __restrict__ whhb,
                             const float* __restrict__ bihf, const float* __restrict__ bhhf,
                             const float* __restrict__ bihb, const float* __restrict__ bhhb,
                             unsigned short* __restrict__ xb, unsigned short* __restrict__ wih,
                             unsigned short* __restrict__ whh, float* __restrict__ bias)
{
    int v = blockIdx.x * 256 + threadIdx.x;   // 0..1048575
    {   // embedding: x[row][col4..col4+3]
        int row = v >> 7;
        int col4 = (v & 127) * 4;
        int id = ids[row];
        float4 e;
        if (id != 0) e = *(const float4*)(emb + (size_t)id * 512 + col4);
        else { e.x = 0.f; e.y = 0.f; e.z = 0.f; e.w = 0.f; }
        us4 o; o.x = f2b(e.x); o.y = f2b(e.y); o.z = f2b(e.z); o.w = f2b(e.w);
        *(us4*)(xb + (size_t)row * 512 + col4) = o;
    }
    if (v < 262144) {   // weight convert + bias sums
        float4 a; us4 o;
        a = ((const float4*)wihf)[v];
        o.x = f2b(a.x); o.y = f2b(a.y); o.z = f2b(a.z); o.w = f2b(a.w);
        *(us4*)(wih + (size_t)v * 4) = o;
        a = ((const float4*)whhf)[v];
        o.x = f2b(a.x); o.y = f2b(a.y); o.z = f2b(a.z); o.w = f2b(a.w);
        *(us4*)(whh + (size_t)v * 4) = o;
        a = ((const float4*)wihb)[v];
        o.x = f2b(a.x); o.y = f2b(a.y); o.z = f2b(a.z); o.w = f2b(a.w);
        *(us4*)(wih + 1048576 + (size_t)v * 4) = o;
        a = ((const float4*)whhb)[v];
        o.x = f2b(a.x); o.y = f2b(a.y); o.z = f2b(a.z); o.w = f2b(a.w);
        *(us4*)(whh + 1048576 + (size_t)v * 4) = o;
        if (v < 2048)      bias[v] = bihf[v] + bhhf[v];
        else if (v < 4096) bias[v] = bihb[v - 2048] + bhhb[v - 2048];
    }
}

// ---------------- persistent bidirectional LSTM, XCD-colocated L2 exchange ----------------
// grid 256, 1 WG/CU (forced by 108KB LDS), so every XCD hosts exactly 32 WGs.
// Each WG reads its physical XCC_ID and claims a column slot on its XCD:
//   XCD0 -> forward direction, XCD1 -> backward, XCD2..7 exit.
// All 32 WGs of a direction share ONE L2, so the h/flag exchange uses plain
// write-back stores + sc0 (L1-bypass) flag loads at L2 latency (~250cy/leg)
// instead of agent-scope IF$ round trips (~900cy/leg). Step body = round-0's
// proven structure. Spin loops are capped so a wrong placement assumption
// fails visibly (bad result) instead of hanging.
__global__ __launch_bounds__(256, 1) void lstm_rec(const unsigned short* __restrict__ whh,
                                                   const unsigned short* __restrict__ wih,
                                                   const unsigned short* __restrict__ xb,
                                                   const float* __restrict__ bias,
                                                   unsigned short* __restrict__ h_all,
                                                   unsigned int* __restrict__ cnt,
                                                   unsigned int* __restrict__ claim)
{
    __shared__ unsigned short hbuf[32][520];      // h_{t-1} staging
    __shared__ unsigned short xbuf[2][32][520];   // x_t staging, double-buffered
    __shared__ float gbuf[4][32][16];             // gate pre-activations
    __shared__ int sinfo[2];                      // {dir, slot}

    const int tid = threadIdx.x;

    // ---- XCD claim: dir = physical XCD (0/1), slot = column group ----
    if (tid == 0) {
        // HW_REG_XCC_ID = id 20, offset 0, size 4  [measured: learn_hip m09]
        unsigned int x = __builtin_amdgcn_s_getreg((3u << 11) | (0u << 6) | 20u) & 7u;
        int dir = -1, slot = 99;
        if (x < 2u) { slot = (int)atomicAdd(&claim[x], 1u); dir = (int)x; }
        sinfo[0] = (slot < NWG) ? dir : -1;
        sinfo[1] = slot;
    }
    __syncthreads();
    const int dir = sinfo[0];
    const int wg  = sinfo[1];
    if (dir < 0) return;                          // 6 of 8 XCDs idle

    const int js = wg * 16;
    const int wave = tid >> 6, lane = tid & 63;
    const int quad = lane >> 4, r16 = lane & 15;
    const int colw = wave * 512 + js + r16;       // gate-row in whh/wih

    // B-fragments: this WG's w_hh and w_ih slices, in registers
    bf16x8 wfr[16], xfr[16];
    {
        const unsigned short* wrow = whh + (size_t)dir * GG * HH + (size_t)colw * 512;
        const unsigned short* xrow = wih + (size_t)dir * GG * EE + (size_t)colw * 512;
#pragma unroll
        for (int kc = 0; kc < 16; ++kc) {
            wfr[kc] = *(const bf16x8*)(wrow + kc * 32 + quad * 8);
            xfr[kc] = *(const bf16x8*)(xrow + kc * 32 + quad * 8);
        }
    }
    const float bsw = bias[dir * GG + colw];

    // cell state in registers: thread owns (b = tid>>3, j = js + 2*(tid&7) + {0,1})
    const int cb = tid >> 3, cj = (tid & 7) * 2;
    float cr0 = 0.f, cr1 = 0.f;

    unsigned short* hd = h_all + (size_t)dir * TT * BB * HH;
    unsigned int* flg = cnt + dir * NWG;
    const ull* xbsrc = (const ull*)xb;            // 128 ull per 512-col row

    // prologue: stage x for the first step into xbuf[0]
    {
        const int te0 = dir ? (TT - 1) : 0;
#pragma unroll
        for (int i = 0; i < 16; ++i) {
            int v = tid + i * 256;
            int row = v >> 7, wi = v & 127;
            ull xv = xbsrc[((size_t)(row << 8) + te0) * 128 + wi];
            *(ull*)&xbuf[0][row][wi * 4] = xv;
        }
    }
    __syncthreads();
    int buf = 0;

    for (int t = 0; t < TT; ++t) {
        const int te = dir ? (TT - 1 - t) : t;

        // issue next step's x prefetch (held in regs; written to LDS at step end)
        ull xpre[16];
        if (t + 1 < TT) {
            const int tn = dir ? (te - 1) : (te + 1);
#pragma unroll
            for (int i = 0; i < 16; ++i) {
                int v = tid + i * 256;
                int row = v >> 7, wi = v & 127;
                xpre[i] = xbsrc[((size_t)(row << 8) + tn) * 128 + wi];
            }
        }

        // ---- x-MFMA: acc := x_t @ Wih^T (fills peer-flag arrival time) ----
        f32x4 alo = {0.f, 0.f, 0.f, 0.f}, ahi = {0.f, 0.f, 0.f, 0.f};
#pragma unroll
        for (int kc = 0; kc < 16; ++kc) {
            const int ko = kc * 32 + quad * 8;
            bf16x8 aflo = *(const bf16x8*)&xbuf[buf][r16][ko];
            bf16x8 afhi = *(const bf16x8*)&xbuf[buf][16 + r16][ko];
            alo = __builtin_amdgcn_mfma_f32_16x16x32_bf16(aflo, xfr[kc], alo, 0, 0, 0);
            ahi = __builtin_amdgcn_mfma_f32_16x16x32_bf16(afhi, xfr[kc], ahi, 0, 0, 0);
        }

        // ---- h rendezvous (L2-local): sc0 flag poll -> plain gather -> h-MFMA ----
        if (t > 0) {
            if (wave == 0) {
                const unsigned int tgt = (unsigned int)t;
                const unsigned int* fp = flg + (lane & 31);
                int guard = 0;
                for (;;) {
                    unsigned int f;
                    asm volatile("global_load_dword %0, %1, off sc0\n\t"
                                 "s_waitcnt vmcnt(0)"
                                 : "=v"(f) : "v"(fp) : "memory");
                    if (__ballot(f >= tgt) == ~0ull) break;
                    if (++guard > (1 << 22)) break;   // no-hang insurance
                }
            }
            __syncthreads();
            const int tp = dir ? (te + 1) : (te - 1);
            const ull* hsrc = (const ull*)(hd + (size_t)tp * BB * HH);
            ull hv[16];
#pragma unroll
            for (int i = 0; i < 16; ++i)
                hv[i] = hsrc[tid + i * 256];          // plain: first-touch, L2-hit
#pragma unroll
            for (int i = 0; i < 16; ++i) {
                int v = tid + i * 256;
                *(ull*)&hbuf[v >> 7][(v & 127) * 4] = hv[i];
            }
            __syncthreads();   // B1: hbuf ready

#pragma unroll
            for (int kc = 0; kc < 16; ++kc) {
                const int ko = kc * 32 + quad * 8;
                bf16x8 aflo = *(const bf16x8*)&hbuf[r16][ko];
                bf16x8 afhi = *(const bf16x8*)&hbuf[16 + r16][ko];
                alo = __builtin_amdgcn_mfma_f32_16x16x32_bf16(aflo, wfr[kc], alo, 0, 0, 0);
                ahi = __builtin_amdgcn_mfma_f32_16x16x32_bf16(afhi, wfr[kc], ahi, 0, 0, 0);
            }
        }

#pragma unroll
        for (int r = 0; r < 4; ++r) {
            gbuf[wave][quad * 4 + r][r16]      = alo[r] + bsw;
            gbuf[wave][16 + quad * 4 + r][r16] = ahi[r] + bsw;
        }
        __syncthreads();   // B2: gbuf ready (and all hbuf reads done)

        // nonlinearity + plain h store (stays in this XCD's L2)
        {
            float2 iv = *(const float2*)&gbuf[0][cb][cj];
            float2 fv = *(const float2*)&gbuf[1][cb][cj];
            float2 gv = *(const float2*)&gbuf[2][cb][cj];
            float2 ov = *(const float2*)&gbuf[3][cb][cj];
            cr0 = sigm(fv.x) * cr0 + sigm(iv.x) * tanh_f(gv.x);
            cr1 = sigm(fv.y) * cr1 + sigm(iv.y) * tanh_f(gv.y);
            float h0 = sigm(ov.x) * tanh_f(cr0);
            float h1 = sigm(ov.y) * tanh_f(cr1);
            unsigned int packed = (unsigned int)f2b(h0) | ((unsigned int)f2b(h1) << 16);
            *(volatile unsigned int*)(hd + (size_t)te * BB * HH + cb * 512 + js + cj) = packed;
        }

        // write prefetched x into the other buffer (overlaps h-store drain)
        if (t + 1 < TT) {
#pragma unroll
            for (int i = 0; i < 16; ++i) {
                int v = tid + i * 256;
                *(ull*)&xbuf[buf ^ 1][v >> 7][(v & 127) * 4] = xpre[i];
            }
            buf ^= 1;
        }
        asm volatile("s_waitcnt vmcnt(0)" ::: "memory");   // h stores at L2
        __syncthreads();   // B3: all waves drained + xbuf[new] ready
        if (tid == 0)
            *(volatile unsigned int*)(flg + wg) = (unsigned int)(t + 1);
    }
}

// ---------------- classifier: logits = [hf|hb] @ cls_w^T + cls_b ----------------
__global__ __launch_bounds__(256) void logits_k(const unsigned short* __restrict__ h_all,
                                                const float* __restrict__ clsw,
                                                const float* __restrict__ clsb,
                                                float* __restrict__ logits)
{
    const int tid = threadIdx.x;
    const int wave = tid >> 6, lane = tid & 63;
    const int wgid = blockIdx.x * 4 + wave;    // 0..1023

    unsigned int wreg[9][8];
#pragma unroll
    for (int c = 0; c < 9; ++c)
#pragma unroll
        for (int q = 0; q < 8; ++q) {
            float w0 = clsw[c * 1024 + (2 * q) * 64 + lane];
            float w1 = clsw[c * 1024 + (2 * q + 1) * 64 + lane];
            wreg[c][q] = (unsigned int)f2b(w0) | ((unsigned int)f2b(w1) << 16);
        }

    const unsigned short* hfb = h_all;
    const unsigned short* hbb = h_all + (size_t)TT * BB * HH;

    for (int i = 0; i < 8; ++i) {
        int m = wgid * 8 + i;                  // m = b*256 + t
        int b = m >> 8, t = m & 255;
        const unsigned short* hf = hfb + ((size_t)t * BB + b) * HH;
        const unsigned short* hb = hbb + ((size_t)t * BB + b) * HH;
        float acc[9];
#pragma unroll
        for (int c = 0; c < 9; ++c) acc[c] = 0.f;
#pragma unroll
        for (int u = 0; u < 16; ++u) {
            const unsigned short* src = (u < 8) ? (hf + u * 64) : (hb + (u - 8) * 64);
            float hv = b2f(src[lane]);
#pragma unroll
            for (int c = 0; c < 9; ++c) {
                unsigned short wv = (u & 1) ? (unsigned short)(wreg[c][u >> 1] >> 16)
                                            : (unsigned short)(wreg[c][u >> 1] & 0xFFFFu);
                acc[c] += hv * b2f(wv);
            }
        }
#pragma unroll
        for (int c = 0; c < 9; ++c) {
            float s = acc[c];
            for (int off = 32; off > 0; off >>= 1) s += __shfl_down(s, off);
            if (lane == 0) logits[(size_t)m * 9 + c] = s + clsb[c];
        }
    }
}

// ---------------- CRF log-likelihood per sequence ----------------
__global__ void crf_k(const float* __restrict__ logits, const int* __restrict__ label,
                      const float* __restrict__ startp, const float* __restrict__ endp,
                      const float* __restrict__ trans, float* __restrict__ llh)
{
    const int b = blockIdx.x;
    const int lane = threadIdx.x;   // 64
    __shared__ float tr[81];
    __shared__ float alpha[9];
    __shared__ int tags[TT];
    for (int v = lane; v < 81; v += 64) tr[v] = trans[v];
    for (int v = lane; v < TT; v += 64) tags[v] = label[b * TT + v];
    __syncthreads();
    const float* lg = logits + (size_t)b * TT * 9;

    float part = 0.f; int mcnt = 0;
    for (int t = lane; t < TT; t += 64) {
        int tg = tags[t];
        bool m = tg > -1;
        if (m) mcnt++;
        if (t == 0)      part += startp[tg] + lg[tg];
        else if (m)      part += lg[t * 9 + tg] + tr[tags[t - 1] * 9 + tg];
    }
    for (int off = 32; off > 0; off >>= 1) {
        part += __shfl_down(part, off);
        mcnt += __shfl_down(mcnt, off);
    }
    part = __shfl(part, 0);
    mcnt = __shfl(mcnt, 0);
    float num = part + endp[tags[mcnt - 1]];

    if (lane < 9) alpha[lane] = startp[lane] + lg[lane];
    __syncthreads();
    for (int t = 1; t < TT; ++t) {
        float nxt = 0.f;
        if (lane < 9) {
            float mx = -1e30f;
#pragma unroll
            for (int c1 = 0; c1 < 9; ++c1) mx = fmaxf(mx, alpha[c1] + tr[c1 * 9 + lane]);
            float s = 0.f;
#pragma unroll
            for (int c1 = 0; c1 < 9; ++c1) s += __expf(alpha[c1] + tr[c1 * 9 + lane] - mx);
            nxt = mx + __logf(s) + lg[t * 9 + lane];
            if (tags[t] <= -1) nxt = alpha[lane];
        }
        __syncthreads();
        if (lane < 9) alpha[lane] = nxt;
        __syncthreads();
    }
    if (lane == 0) {
        float mx = -1e30f;
#pragma unroll
        for (int c = 0; c < 9; ++c) mx = fmaxf(mx, alpha[c] + endp[c]);
        float s = 0.f;
#pragma unroll
        for (int c = 0; c < 9; ++c) s += __expf(alpha[c] + endp[c] - mx);
        llh[b] = num - (mx + __logf(s));
    }
}

__global__ void fin_k(const float* __restrict__ llh, float* __restrict__ out)
{
    int lane = threadIdx.x;
    float v = (lane < 32) ? llh[lane] : 0.f;
    for (int off = 32; off > 0; off >>= 1) v += __shfl_down(v, off);
    if (lane == 0) out[0] = -v * (1.f / 32.f);
}

// ---------------- launch ----------------
extern "C" void kernel_launch(void* const* d_in, const int* in_sizes, int n_in,
                              void* d_out, int out_size, void* d_ws, size_t ws_size,
                              hipStream_t stream)
{
    const int*   ids   = (const int*)  d_in[0];
    const int*   label = (const int*)  d_in[1];
    const float* emb   = (const float*)d_in[2];
    const float* wihf  = (const float*)d_in[3];
    const float* whhf  = (const float*)d_in[4];
    const float* bihf  = (const float*)d_in[5];
    const float* bhhf  = (const float*)d_in[6];
    const float* wihb  = (const float*)d_in[7];
    const float* whhb  = (const float*)d_in[8];
    const float* bihb  = (const float*)d_in[9];
    const float* bhhb  = (const float*)d_in[10];
    const float* clsw  = (const float*)d_in[11];
    const float* clsb  = (const float*)d_in[12];
    const float* stp   = (const float*)d_in[13];
    const float* enp   = (const float*)d_in[14];
    const float* trp   = (const float*)d_in[15];

    char* ws = (char*)d_ws;
    unsigned short* xb   = (unsigned short*)(ws + 0);           //  8 MB  [8192][512] bf16
    unsigned short* wih  = (unsigned short*)(ws + 8388608);     //  4 MB  [2][2048][512]
    unsigned short* whh  = (unsigned short*)(ws + 12582912);    //  4 MB  [2][2048][512]
    float*          bias = (float*)(ws + 16777216);             // 16 KB  [2][2048]
    unsigned short* hall = (unsigned short*)(ws + 16793600);    // 16 MB  [2][256][32][512]
    float*          lgt  = (float*)(ws + 33570816);             // 288 KB [8192][9]
    float*          llh  = (float*)(ws + 33865728);             // 128 B
    unsigned int*   cnt  = (unsigned int*)(ws + 33865856);      // flags [2][32]
    unsigned int*   clm  = (unsigned int*)(ws + 33866112);      // claim [8]

    hipMemsetAsync(cnt, 0, 512, stream);   // flags + claim counters
    prep_embed_k<<<4096, 256, 0, stream>>>(ids, emb, wihf, whhf, wihb, whhb,
                                           bihf, bhhf, bihb, bhhb, xb, wih, whh, bias);
    lstm_rec<<<256, 256, 0, stream>>>(whh, wih, xb, bias, hall, cnt, clm);
    logits_k<<<256, 256, 0, stream>>>(hall, clsw, clsb, lgt);
    crf_k<<<32, 64, 0, stream>>>(lgt, label, stp, enp, trp, llh);
    fin_k<<<1, 64, 0, stream>>>(llh, (float*)d_out);
}